// Round 9
// baseline (213.815 us; speedup 1.0000x reference)
//
#include <hip/hip_runtime.h>
#include <hip/hip_bf16.h>

// GDGCN: out[b,c,m,t] = sum_n softmax_row(relu(t1 nv2^T))[n,m] * x[b,c,n,t]
// t1 = nv1 @ (sum_d tv[d] k[d,:,:]);  N=8192, D=32, cols = B*C*T = 192.
// R9: k_mega rebuilt around 32x32x16 MFMA with a REGISTER-SPACE C->B
// transform (8 packed shfl_xor(32) + selects per 32n x 32m E-tile):
// each wave privately owns 32 m x 192 cols — ZERO LDS, ZERO barriers,
// fully independent wave pipelines. Small kernels unchanged from R8.

#define NN 8192
#define DD 32
#define TT 12
#define NSPLIT 8
#define CHUNK 1024

typedef __attribute__((ext_vector_type(8))) short bf16x8;
typedef __attribute__((ext_vector_type(4))) short bf16x4;
typedef __attribute__((ext_vector_type(4))) float f32x4;
typedef __attribute__((ext_vector_type(16))) float f32x16;

static __device__ __forceinline__ unsigned short f2bf(float f) {
  unsigned int u = __float_as_uint(f);
  u = (u + 0x7FFFu + ((u >> 16) & 1u)) >> 16;  // RNE bf16
  return (unsigned short)u;
}

static __device__ __forceinline__ unsigned int pk2(float lo, float hi) {
  return (unsigned int)f2bf(lo) | ((unsigned int)f2bf(hi) << 16);
}

static __device__ __forceinline__ float fexp2(float x) {
#if __has_builtin(__builtin_amdgcn_exp2f)
  return __builtin_amdgcn_exp2f(x);
#else
  return __builtin_exp2f(x);
#endif
}

// ---- fused: core = tv.k ; t1 = (nv1@core)*log2e (bf16) ; nv2 -> bf16 ; sums=0
__global__ __launch_bounds__(256) void k_prep(const float* __restrict__ nv1,
                                              const float* __restrict__ nv2,
                                              const float* __restrict__ timevec,
                                              const float* __restrict__ kk,
                                              const int* __restrict__ tind,
                                              unsigned short* __restrict__ t1b,
                                              unsigned short* __restrict__ nv2b,
                                              float* __restrict__ sums) {
  __shared__ float cs[1024];
  const int tid = threadIdx.x;
  if (tid < 128) sums[blockIdx.x * 128 + tid] = 0.f;
  const float* tv = timevec + (size_t)tind[0] * DD;
  for (int idx = tid; idx < 1024; idx += 256) {
    float acc = 0.f;
#pragma unroll
    for (int d = 0; d < DD; ++d) acc += tv[d] * kk[d * 1024 + idx];
    cs[idx] = acc;
  }
  __syncthreads();
  const int nbase = blockIdx.x * 128;
  const int f = tid & 31, sub = tid >> 5;
#pragma unroll 4
  for (int it = 0; it < 16; ++it) {
    const int n = nbase + it * 8 + sub;
    const float* nr = nv1 + (size_t)n * DD;
    float acc = 0.f;
#pragma unroll
    for (int e = 0; e < DD; ++e) acc += nr[e] * cs[e * DD + f];
    t1b[(size_t)n * DD + f] = f2bf(acc * 1.4426950408889634f);  // fold log2(e)
  }
#pragma unroll 4
  for (int it = 0; it < 16; ++it) {
    const int idx = nbase * DD + it * 256 + tid;
    nv2b[idx] = f2bf(nv2[idx]);
  }
}

// ---- sums[n] += sum_m exp2(relu(t1[n].nv2[m]))  grid (128 n, 8 m-chunks) ----
__global__ __launch_bounds__(256) void k_stats(const unsigned short* __restrict__ t1b,
                                               const unsigned short* __restrict__ nv2b,
                                               float* __restrict__ sums) {
  const int tid = threadIdx.x;
  const int w = tid >> 6, lane = tid & 63, q = lane >> 4, i16 = lane & 15;
  const int nbase = blockIdx.x * 64 + w * 16;
  bf16x8 a = *(const bf16x8*)(t1b + (size_t)(nbase + i16) * DD + q * 8);
  const f32x4 z4 = {0.f, 0.f, 0.f, 0.f};
  float s[4] = {0.f, 0.f, 0.f, 0.f};
  const int m0 = blockIdx.y * 1024;
  for (int mt = m0; mt < m0 + 1024; mt += 64) {
#pragma unroll
    for (int u = 0; u < 4; ++u) {
      bf16x8 b = *(const bf16x8*)(nv2b + (size_t)(mt + u * 16 + i16) * DD + q * 8);
      f32x4 d = __builtin_amdgcn_mfma_f32_16x16x32_bf16(a, b, z4, 0, 0, 0);
#pragma unroll
      for (int r = 0; r < 4; ++r) s[r] += fexp2(fmaxf(d[r], 0.f));
    }
  }
#pragma unroll
  for (int r = 0; r < 4; ++r)
    for (int off = 1; off < 16; off <<= 1) s[r] += __shfl_xor(s[r], off, 64);
  if (i16 == 0) {
#pragma unroll
    for (int r = 0; r < 4; ++r) atomicAdd(&sums[nbase + q * 4 + r], s[r]);
  }
}

// ---- yT[col][n] = bf16(x[bc][n][t] / sums[n]) via LDS transpose ----
__global__ __launch_bounds__(256) void k_y(const float* __restrict__ x,
                                           const float* __restrict__ sums,
                                           unsigned short* __restrict__ yT) {
  __shared__ float xs[3072];
  const int tid = threadIdx.x;
  const int n0 = blockIdx.x * 256;
  const int bc = blockIdx.y;
  const float* xp = x + (size_t)bc * NN * TT + (size_t)n0 * TT;
#pragma unroll
  for (int j = 0; j < 12; ++j) xs[j * 256 + tid] = xp[j * 256 + tid];
  __syncthreads();
  const float rinv = 1.0f / sums[n0 + tid];
#pragma unroll
  for (int t = 0; t < 12; ++t)
    yT[(size_t)(bc * TT + t) * NN + n0 + tid] = f2bf(xs[tid * 12 + t] * rinv);
}

// ---- k_mega: part[nc][col][m] = sum_{n in chunk} E[n][m] * y[col][n] ----
// grid (64 m-blocks of 128, 8 chunks); 256 thr = 4 waves; wave w privately
// owns m-strip [mb + w*32, +32) x all 192 cols. Per 32-n iter:
//   gen: 2 chained 32x32x16 MFMAs -> D[n][m] (16 regs, C-layout)
//   E = exp2(max(D,0)) -> pack bf16 pairs -> 8 shfl_xor(32) + selects
//       produce the two B-operand k-half fragments IN REGISTERS
//   acc: 6 col-frags x 2 k-halves = 12 MFMAs into 6 f32x16 accs.
// No LDS, no barriers. Epilogue scatters C-layout to part (coalesced in m).
__global__ __launch_bounds__(256, 2) void k_mega(const unsigned short* __restrict__ t1b,
                                                 const unsigned short* __restrict__ nv2b,
                                                 const unsigned short* __restrict__ yT,
                                                 float* __restrict__ part) {
  const int tid = threadIdx.x;
  const int w = tid >> 6, lane = tid & 63;
  const int h = lane >> 5, m31 = lane & 31;
  const int mw = blockIdx.x * 128 + w * 32;
  const int nt0 = blockIdx.y * CHUNK;

  // invariant nv2 B-frags for gen: B[k=h*8+j][m=m31] = nv2[mw+m31][kh*16 + h*8 + j]
  bf16x8 bn0 = *(const bf16x8*)(nv2b + (size_t)(mw + m31) * DD + h * 8);
  bf16x8 bn1 = *(const bf16x8*)(nv2b + (size_t)(mw + m31) * DD + 16 + h * 8);

  f32x16 acc[6];
#pragma unroll
  for (int c = 0; c < 6; ++c)
#pragma unroll
    for (int r = 0; r < 16; ++r) acc[c][r] = 0.f;
  f32x16 z16;
#pragma unroll
  for (int r = 0; r < 16; ++r) z16[r] = 0.f;

  // t1 A-frag prefetch: A[n=m31][k=h*8+j] = t1[nt+m31][kh*16 + h*8 + j]
  bf16x8 ta0 = *(const bf16x8*)(t1b + (size_t)(nt0 + m31) * DD + h * 8);
  bf16x8 ta1 = *(const bf16x8*)(t1b + (size_t)(nt0 + m31) * DD + 16 + h * 8);

  for (int nt = nt0; nt < nt0 + CHUNK; nt += 32) {
    // y A-frags (12 b128 from L2), issued first
    bf16x8 yf[6][2];
#pragma unroll
    for (int c = 0; c < 6; ++c) {
      const unsigned short* yp = yT + (size_t)(c * 32 + m31) * NN + nt + h * 8;
      yf[c][0] = *(const bf16x8*)(yp);
      yf[c][1] = *(const bf16x8*)(yp + 16);
    }

    // gen logits: D[n][m] over 32n x 32m, K=32 via two chained K=16 MFMAs
    f32x16 d = __builtin_amdgcn_mfma_f32_32x32x16_bf16(ta1, bn1, z16, 0, 0, 0);
    d = __builtin_amdgcn_mfma_f32_32x32x16_bf16(ta0, bn0, d, 0, 0, 0);

    // prefetch next iter's t1
    if (nt + 32 < nt0 + CHUNK) {
      ta0 = *(const bf16x8*)(t1b + (size_t)(nt + 32 + m31) * DD + h * 8);
      ta1 = *(const bf16x8*)(t1b + (size_t)(nt + 32 + m31) * DD + 16 + h * 8);
    }

    // E = exp2(max(d,0)); C-layout reg r holds n = (r&3) + 8*(r>>2) + 4*h
    float e[16];
#pragma unroll
    for (int r = 0; r < 16; ++r) e[r] = fexp2(fmaxf(d[r], 0.f));

    // register C->B transform: B_kh[slot 4a+b] = E-reg[4*(2kh+h)+b] of half a
    unsigned int frag[2][4];
#pragma unroll
    for (int kh = 0; kh < 2; ++kh) {
#pragma unroll
      for (int b = 0; b < 4; b += 2) {
        unsigned int P0 = pk2(e[8 * kh + b], e[8 * kh + b + 1]);          // regs for half0 targets
        unsigned int P1 = pk2(e[8 * kh + 4 + b], e[8 * kh + 5 + b]);      // regs for half1 targets
        unsigned int S0 = __shfl_xor(P0, 32, 64);
        unsigned int S1 = __shfl_xor(P1, 32, 64);
        frag[kh][b >> 1] = h ? S1 : P0;        // slots j = b, b+1     (a = 0)
        frag[kh][2 + (b >> 1)] = h ? P1 : S0;  // slots j = 4+b, 5+b   (a = 1)
      }
    }
    bf16x8 ef0, ef1;
    __builtin_memcpy(&ef0, &frag[0][0], 16);
    __builtin_memcpy(&ef1, &frag[1][0], 16);

    // accumulate: out[col][m] += y[col][n] * E[n][m]
#pragma unroll
    for (int c = 0; c < 6; ++c) {
      acc[c] = __builtin_amdgcn_mfma_f32_32x32x16_bf16(yf[c][0], ef0, acc[c], 0, 0, 0);
      acc[c] = __builtin_amdgcn_mfma_f32_32x32x16_bf16(yf[c][1], ef1, acc[c], 0, 0, 0);
    }
  }

  // epilogue: acc[c] reg r -> col = c*32 + (r&3) + 8*(r>>2) + 4*h, m = mw + m31
  float* pp = part + (size_t)blockIdx.y * 192 * NN;
#pragma unroll
  for (int c = 0; c < 6; ++c)
#pragma unroll
    for (int r = 0; r < 16; ++r) {
      const int col = c * 32 + (r & 3) + 8 * (r >> 2) + 4 * h;
      pp[(size_t)col * NN + mw + m31] = acc[c][r];
    }
}

// ---- reduce NSPLIT partials + transpose to out[bc][m][t] ----
__global__ __launch_bounds__(256) void k_reduce(const float* __restrict__ part,
                                                float* __restrict__ out) {
  __shared__ float os[3072];
  const int tid = threadIdx.x;
  const int m0 = blockIdx.x * 256;
  const int bc = blockIdx.y;
#pragma unroll
  for (int t = 0; t < 12; ++t) {
    const int col = bc * TT + t;
    float s = 0.f;
#pragma unroll
    for (int nc = 0; nc < NSPLIT; ++nc)
      s += part[((size_t)nc * 192 + col) * NN + m0 + tid];
    os[tid * 12 + t] = s;
  }
  __syncthreads();
  float* op = out + (size_t)bc * NN * TT + (size_t)m0 * TT;
#pragma unroll
  for (int j = 0; j < 12; ++j) op[j * 256 + tid] = os[j * 256 + tid];
}

extern "C" void kernel_launch(void* const* d_in, const int* in_sizes, int n_in,
                              void* d_out, int out_size, void* d_ws, size_t ws_size,
                              hipStream_t stream) {
  const float* x = (const float*)d_in[0];
  const float* nv1 = (const float*)d_in[1];
  const float* nv2 = (const float*)d_in[2];
  const float* tv = (const float*)d_in[3];
  const float* kk = (const float*)d_in[4];
  const int* tind = (const int*)d_in[5];
  float* out = (float*)d_out;

  char* ws = (char*)d_ws;
  unsigned short* t1b  = (unsigned short*)(ws);            //  524288 B
  unsigned short* nv2b = (unsigned short*)(ws + 524288);   //  524288 B
  float* sums          = (float*)(ws + 1048576);           //   32768 B
  unsigned short* yT   = (unsigned short*)(ws + 1081344);  // 3145728 B -> 4227072
  float* part          = (float*)(ws + 4227072);           // 50331648 B -> 54558720

  k_prep<<<64, 256, 0, stream>>>(nv1, nv2, tv, kk, tind, t1b, nv2b, sums);
  k_stats<<<dim3(128, 8), 256, 0, stream>>>(t1b, nv2b, sums);
  k_y<<<dim3(32, 16), 256, 0, stream>>>(x, sums, yT);
  k_mega<<<dim3(64, NSPLIT), 256, 0, stream>>>(t1b, nv2b, yT, part);
  k_reduce<<<dim3(32, 16), 256, 0, stream>>>(part, out);
}